// Round 9
// baseline (571.722 us; speedup 1.0000x reference)
//
#include <hip/hip_runtime.h>

// EdgeModel: out = relu(x@W1+b1)@W2 + b2 + x, x = [src|dest|ea|u[batch]].
// E=1e6, dims 128. bf16 MFMA 16x16x32, fp32 accum, fp32 residual.
// R9: x staged HBM->LDS via global_load_lds width=16 (no staging registers),
// fp32 xs, LDS-linear dest + inverse-swizzled global source + swizzled reads
// (involution: gran ^= row&15 on 16B granules). 48 KB LDS + ~150 unified regs
// -> __launch_bounds__(256,3) = 3 blocks/CU without spills. 2 barriers/tile;
// next tile's loads issued after bar2, in flight under GEMM2+stores.

#define E_TOTAL   1000000
#define TILE_M    64
#define NUM_TILES (E_TOTAL / TILE_M)   // 15625
#define GRID      2048

typedef __attribute__((ext_vector_type(8))) __bf16 bf16x8;
typedef __attribute__((ext_vector_type(4))) __bf16 bf16x4;
typedef __attribute__((ext_vector_type(4))) float  f32x4;

typedef const __attribute__((address_space(1))) unsigned GASu;
typedef __attribute__((address_space(3))) unsigned LASu;

__device__ __forceinline__ void cp16(const void* g, void* l) {
    __builtin_amdgcn_global_load_lds((GASu*)g, (LASu*)l, 16, 0, 0);
}

__device__ __forceinline__ bf16x8 pack8(f32x4 v0, f32x4 v1) {
    bf16x8 r;
    r[0] = (__bf16)v0[0]; r[1] = (__bf16)v0[1];
    r[2] = (__bf16)v0[2]; r[3] = (__bf16)v0[3];
    r[4] = (__bf16)v1[0]; r[5] = (__bf16)v1[1];
    r[6] = (__bf16)v1[2]; r[7] = (__bf16)v1[3];
    return r;
}

// hl: row-major [64][128] bf16, 16 groups of 8/row, group XOR (row&15).
__device__ __forceinline__ int swz(int row, int group) {
    return (row * 16 + (group ^ (row & 15))) * 8;
}

// xs: [64][128] fp32, LDS-linear; LDS granule g of row holds SOURCE granule
// g ^ (row&15). Read source granule s at LDS granule s ^ (row&15).
__device__ __forceinline__ f32x4 xrd(const float* xs, int row, int sgran) {
    return *(const f32x4*)&xs[row * 128 + ((sgran ^ (row & 15)) << 2)];
}

__global__ __launch_bounds__(256, 3)
void edge_mlp(const float* __restrict__ gsrc,
              const float* __restrict__ gdst,
              const float* __restrict__ gea,
              const float* __restrict__ gu,
              const int*   __restrict__ gbatch,
              const float* __restrict__ gw1,
              const float* __restrict__ gb1,
              const float* __restrict__ gw2,
              const float* __restrict__ gb2,
              float* __restrict__ gout)
{
    __shared__ __align__(16) float  xs[TILE_M * 128];   // 32 KB, fp32, swizzled content
    __shared__ __align__(16) __bf16 hl[TILE_M * 128];   // 16 KB, bf16, swizzled

    const int tid  = threadIdx.x;
    const int lane = tid & 63;
    const int wid  = tid >> 6;     // wave owns hidden/out-dim rows [wb,wb+32)
    const int l15  = lane & 15;
    const int g    = lane >> 4;
    const int wb   = wid * 32;

    // ---- W1^T, W2^T as A-fragments (registers, once per block) ----
    bf16x8 w1t[2][4], w2t[2][4];
#pragma unroll
    for (int m = 0; m < 2; ++m)
#pragma unroll
        for (int ks = 0; ks < 4; ++ks) {
            bf16x8 t1, t2;
#pragma unroll
            for (int j = 0; j < 8; ++j) {
                const int k = ks * 32 + g * 8 + j;
                const int r = wb + m * 16 + l15;
                t1[j] = (__bf16)gw1[k * 128 + r];
                t2[j] = (__bf16)gw2[k * 128 + r];
            }
            w1t[m][ks] = t1;
            w2t[m][ks] = t2;
        }

    // ---- biases along C rows: b[wb + m*16 + g*4 + r] ----
    f32x4 b1v[2], b2v[2];
#pragma unroll
    for (int m = 0; m < 2; ++m)
#pragma unroll
        for (int r = 0; r < 4; ++r) {
            b1v[m][r] = gb1[wb + m * 16 + g * 4 + r];
            b2v[m][r] = gb2[wb + m * 16 + g * 4 + r];
        }

    // ---- async stage of one tile: 8 cp16/wave; wave w covers rows
    //      [w*16, w*16+16). Call c: lane -> row = w*16+c*2+(lane>>5),
    //      LDS gran = lane&31, source gran = gran ^ (row&15). ----
    const int srow0 = wid * 16;
    auto issue_loads = [&](int t) {
        const int e0 = t * TILE_M;
#pragma unroll
        for (int c = 0; c < 8; ++c) {
            const int row  = srow0 + c * 2 + (lane >> 5);
            const int gran = lane & 31;
            const int sg   = gran ^ (row & 15);
            const int e    = e0 + row;
            const int bi   = gbatch[e];       // only sg>=24 lanes need it
            // branchless per-lane source pointer
            const float* p = gsrc;
            p = (sg >= 8)  ? gdst : p;
            p = (sg >= 16) ? gea  : p;
            const size_t off = (size_t)((sg >= 24) ? -1 : 0) ?
                               0 : 0; // (placeholder removed below)
            const float* rowp = (sg < 24) ? (p + (size_t)e * 32)
                                          : (gu + (size_t)bi * 32);
            cp16(rowp + (sg & 7) * 4, &xs[(srow0 + c * 2) * 128]);
        }
    };

    int tile = blockIdx.x;
    issue_loads(tile);

    while (true) {
        __syncthreads();   // bar1: vmcnt(0) drain -> xs ready; hl free

        const int e0   = tile * TILE_M;
        const int nxt  = tile + GRID;
        const bool have = nxt < NUM_TILES;

        // ---- GEMM1^T: h^T = W1^T @ x^T + b1 (fp32 xs -> bf16 frags) ----
        f32x4 acc[2][4];
#pragma unroll
        for (int m = 0; m < 2; ++m)
#pragma unroll
            for (int n = 0; n < 4; ++n)
                acc[m][n] = b1v[m];
#pragma unroll
        for (int ks = 0; ks < 4; ++ks) {
            bf16x8 bf[4];
#pragma unroll
            for (int n = 0; n < 4; ++n) {
                const int row = n * 16 + l15;
                f32x4 lo = xrd(xs, row, ks * 8 + g * 2);
                f32x4 hi = xrd(xs, row, ks * 8 + g * 2 + 1);
                bf[n] = pack8(lo, hi);
            }
#pragma unroll
            for (int m = 0; m < 2; ++m)
#pragma unroll
                for (int n = 0; n < 4; ++n)
                    acc[m][n] = __builtin_amdgcn_mfma_f32_16x16x32_bf16(
                        w1t[m][ks], bf[n], acc[m][n], 0, 0, 0);
        }

        // ---- ReLU + pack + h -> hl (b64: 4 consecutive hidden dims) ----
#pragma unroll
        for (int m = 0; m < 2; ++m)
#pragma unroll
            for (int n = 0; n < 4; ++n) {
                f32x4 v = acc[m][n];
                bf16x4 h4;
#pragma unroll
                for (int r = 0; r < 4; ++r) {
                    float x = v[r];
                    h4[r] = (__bf16)(x > 0.f ? x : 0.f);
                }
                const int hid = wb + m * 16 + 4 * g;       // 4-aligned
                *(bf16x4*)&hl[swz(n * 16 + l15, hid >> 3) + (hid & 7)] = h4;
            }

        // ---- acc2 init: b2 + EXACT fp32 residual from xs ----
        f32x4 acc2[2][4];
#pragma unroll
        for (int n = 0; n < 4; ++n) {
            const int row = n * 16 + l15;
#pragma unroll
            for (int m = 0; m < 2; ++m) {
                f32x4 rx = xrd(xs, row, wid * 8 + m * 4 + g);
                f32x4 t;
#pragma unroll
                for (int r = 0; r < 4; ++r)
                    t[r] = b2v[m][r] + rx[r];
                acc2[m][n] = t;
            }
        }
        __syncthreads();   // bar2: hl visible; xs fully consumed

        // ---- issue next tile's loads: overwrite xs, fly under GEMM2 ----
        if (have) issue_loads(nxt);

        // ---- GEMM2^T: out^T += W2^T @ h^T ----
#pragma unroll
        for (int ks = 0; ks < 4; ++ks) {
            bf16x8 bh[4];
#pragma unroll
            for (int n = 0; n < 4; ++n)
                bh[n] = *(const bf16x8*)&hl[swz(n * 16 + l15, ks * 4 + g)];
#pragma unroll
            for (int m = 0; m < 2; ++m)
#pragma unroll
                for (int n = 0; n < 4; ++n)
                    acc2[m][n] = __builtin_amdgcn_mfma_f32_16x16x32_bf16(
                        w2t[m][ks], bh[n], acc2[m][n], 0, 0, 0);
        }

        // ---- epilogue: plain float4 stores (4 consecutive out dims) ----
#pragma unroll
        for (int n = 0; n < 4; ++n) {
            const size_t rowbase = (size_t)(e0 + n * 16 + l15) * 128;
#pragma unroll
            for (int m = 0; m < 2; ++m)
                *(f32x4*)&gout[rowbase + wb + m * 16 + g * 4] = acc2[m][n];
        }

        if (!have) break;
        tile = nxt;
    }
}

extern "C" void kernel_launch(void* const* d_in, const int* in_sizes, int n_in,
                              void* d_out, int out_size, void* d_ws, size_t ws_size,
                              hipStream_t stream) {
    const float* src = (const float*)d_in[0];
    const float* dst = (const float*)d_in[1];
    const float* ea  = (const float*)d_in[2];
    const float* u   = (const float*)d_in[3];
    const int*   bt  = (const int*)d_in[4];
    const float* w1  = (const float*)d_in[5];
    const float* b1  = (const float*)d_in[6];
    const float* w2  = (const float*)d_in[7];
    const float* b2  = (const float*)d_in[8];
    float* out = (float*)d_out;

    edge_mlp<<<GRID, 256, 0, stream>>>(src, dst, ea, u, bt, w1, b1, w2, b2, out);
}

// Round 10
// 296.686 us; speedup vs baseline: 1.9270x; 1.9270x over previous
//
#include <hip/hip_runtime.h>

// EdgeModel: out = relu(x@W1+b1)@W2 + b2 + x, x = [src|dest|ea|u[batch]].
// E=1e6, dims 128. bf16 MFMA 16x16x32, fp32 accum.
// R10: R5 structure EXACTLY (stage x->LDS bf16 swizzled; both GEMMs
// transposed; h->LDS b64; residual from xs; 2 barriers/tile; reg prefetch
// 1 tile ahead) with ONE change: w2t is reloaded from global (L2-resident
// 64KB) each tile instead of held in 32 VGPRs across the loop. Max-live
// drops ~185 -> ~140, so __launch_bounds__(256,3) gives 3 blocks/CU
// WITHOUT the spills that killed R6/R7/R9.

#define E_TOTAL   1000000
#define TILE_M    64
#define NUM_TILES (E_TOTAL / TILE_M)   // 15625
#define GRID      2048

typedef __attribute__((ext_vector_type(8))) __bf16 bf16x8;
typedef __attribute__((ext_vector_type(4))) __bf16 bf16x4;
typedef __attribute__((ext_vector_type(4))) float  f32x4;

__device__ inline bf16x8 pack8(f32x4 v0, f32x4 v1) {
    bf16x8 r;
    r[0] = (__bf16)v0[0]; r[1] = (__bf16)v0[1];
    r[2] = (__bf16)v0[2]; r[3] = (__bf16)v0[3];
    r[4] = (__bf16)v1[0]; r[5] = (__bf16)v1[1];
    r[6] = (__bf16)v1[2]; r[7] = (__bf16)v1[3];
    return r;
}

// row-major [64][128] bf16, 16 groups of 8/row, group XOR (row&15):
// all b128 reads conflict-free.
__device__ inline int swz(int row, int group) {
    return (row * 16 + (group ^ (row & 15))) * 8;
}

__global__ __launch_bounds__(256, 3)
void edge_mlp(const float* __restrict__ gsrc,
              const float* __restrict__ gdst,
              const float* __restrict__ gea,
              const float* __restrict__ gu,
              const int*   __restrict__ gbatch,
              const float* __restrict__ gw1,
              const float* __restrict__ gb1,
              const float* __restrict__ gw2,
              const float* __restrict__ gb2,
              float* __restrict__ gout)
{
    __shared__ __align__(16) __bf16 xs[TILE_M * 128];   // x tile (bf16, swizzled)
    __shared__ __align__(16) __bf16 hl[TILE_M * 128];   // h tile (bf16, swizzled)

    const int tid  = threadIdx.x;
    const int lane = tid & 63;
    const int wid  = tid >> 6;     // wave owns hidden/out-dim rows [wb,wb+32)
    const int l15  = lane & 15;
    const int g    = lane >> 4;
    const int wb   = wid * 32;

    // ---- W1^T as A-fragments (persistent; W2^T reloaded per tile):
    //      lane holds W^T[row = wb+m*16+l15][k = ks*32+g*8+j] = gw[k*128+row]
    bf16x8 w1t[2][4];
#pragma unroll
    for (int m = 0; m < 2; ++m)
#pragma unroll
        for (int ks = 0; ks < 4; ++ks) {
            bf16x8 t1;
#pragma unroll
            for (int j = 0; j < 8; ++j) {
                const int k = ks * 32 + g * 8 + j;
                t1[j] = (__bf16)gw1[k * 128 + (wb + m * 16 + l15)];
            }
            w1t[m][ks] = t1;
        }

    // ---- biases along C rows: b[wb + m*16 + g*4 + r]
    f32x4 b1v[2], b2v[2];
#pragma unroll
    for (int m = 0; m < 2; ++m)
#pragma unroll
        for (int r = 0; r < 4; ++r) {
            b1v[m][r] = gb1[wb + m * 16 + g * 4 + r];
            b2v[m][r] = gb2[wb + m * 16 + g * 4 + r];
        }

    // ---- staging: thread t owns edge-row t>>2, 8-float chunk t&3 ----
    const int srow = tid >> 2;
    const int ssub = tid & 3;

    f32x4 pre[4][2];
    auto load_pre = [&](int t) {
        const int e = t * TILE_M + srow;
        const int bi = gbatch[e];          // first: gates the u gather
        const float* p0 = gsrc + (size_t)e * 32 + ssub * 8;
        const float* p1 = gdst + (size_t)e * 32 + ssub * 8;
        const float* p2 = gea  + (size_t)e * 32 + ssub * 8;
        pre[0][0] = *(const f32x4*)p0; pre[0][1] = *(const f32x4*)(p0 + 4);
        pre[1][0] = *(const f32x4*)p1; pre[1][1] = *(const f32x4*)(p1 + 4);
        pre[2][0] = *(const f32x4*)p2; pre[2][1] = *(const f32x4*)(p2 + 4);
        const float* p3 = gu + (size_t)bi * 32 + ssub * 8;
        pre[3][0] = *(const f32x4*)p3; pre[3][1] = *(const f32x4*)(p3 + 4);
    };

    int tile = blockIdx.x;
    load_pre(tile);

    while (true) {
        // ---- stage x tile into LDS (bf16, swizzled) ----
#pragma unroll
        for (int p = 0; p < 4; ++p)
            *(bf16x8*)&xs[swz(srow, p * 4 + ssub)] = pack8(pre[p][0], pre[p][1]);
        __syncthreads();                                   // bar1

        const int  nxt  = tile + GRID;
        const bool have = nxt < NUM_TILES;
        if (have) load_pre(nxt);

        // ---- GEMM1^T: h^T = W1^T @ x^T + b1 ----
        f32x4 acc[2][4];
#pragma unroll
        for (int m = 0; m < 2; ++m)
#pragma unroll
            for (int n = 0; n < 4; ++n)
                acc[m][n] = b1v[m];
#pragma unroll
        for (int ks = 0; ks < 4; ++ks) {
            bf16x8 bf[4];
#pragma unroll
            for (int n = 0; n < 4; ++n)
                bf[n] = *(const bf16x8*)&xs[swz(n * 16 + l15, ks * 4 + g)];
#pragma unroll
            for (int m = 0; m < 2; ++m)
#pragma unroll
                for (int n = 0; n < 4; ++n)
                    acc[m][n] = __builtin_amdgcn_mfma_f32_16x16x32_bf16(
                        w1t[m][ks], bf[n], acc[m][n], 0, 0, 0);
        }

        // ---- ReLU + pack + h -> LDS (b64: 4 consecutive hidden dims) ----
#pragma unroll
        for (int m = 0; m < 2; ++m)
#pragma unroll
            for (int n = 0; n < 4; ++n) {
                f32x4 v = acc[m][n];
                bf16x4 h4;
#pragma unroll
                for (int r = 0; r < 4; ++r) {
                    float x = v[r];
                    h4[r] = (__bf16)(x > 0.f ? x : 0.f);
                }
                const int hid = wb + m * 16 + 4 * g;       // 4-aligned
                *(bf16x4*)&hl[swz(n * 16 + l15, hid >> 3) + (hid & 7)] = h4;
            }

        // ---- reload W2^T fragments (L2/L3-resident; acc now dead, so this
        //      reuses its register space; ~400cy of cover before first use) ----
        bf16x8 w2t[2][4];
#pragma unroll
        for (int m = 0; m < 2; ++m)
#pragma unroll
            for (int ks = 0; ks < 4; ++ks) {
                bf16x8 t2;
#pragma unroll
                for (int j = 0; j < 8; ++j) {
                    const int k = ks * 32 + g * 8 + j;
                    t2[j] = (__bf16)gw2[k * 128 + (wb + m * 16 + l15)];
                }
                w2t[m][ks] = t2;
            }

        // ---- acc2 init: bias + residual x (b64 read from xs, pre-bar2) ----
        f32x4 acc2[2][4];
#pragma unroll
        for (int m = 0; m < 2; ++m)
#pragma unroll
            for (int n = 0; n < 4; ++n) {
                const int hid = wb + m * 16 + 4 * g;       // out-dim base, 4-aligned
                bf16x4 rx = *(const bf16x4*)&xs[swz(n * 16 + l15, hid >> 3) + (hid & 7)];
                f32x4 t;
#pragma unroll
                for (int r = 0; r < 4; ++r)
                    t[r] = b2v[m][r] + (float)rx[r];
                acc2[m][n] = t;
            }
        __syncthreads();                                   // bar2

        // ---- GEMM2^T: out^T += W2^T @ h^T ----
#pragma unroll
        for (int ks = 0; ks < 4; ++ks) {
            bf16x8 bh[4];
#pragma unroll
            for (int n = 0; n < 4; ++n)
                bh[n] = *(const bf16x8*)&hl[swz(n * 16 + l15, ks * 4 + g)];
#pragma unroll
            for (int m = 0; m < 2; ++m)
#pragma unroll
                for (int n = 0; n < 4; ++n)
                    acc2[m][n] = __builtin_amdgcn_mfma_f32_16x16x32_bf16(
                        w2t[m][ks], bh[n], acc2[m][n], 0, 0, 0);
        }

        // ---- epilogue: plain float4 stores (4 consecutive out dims) ----
        const int e0 = tile * TILE_M;
#pragma unroll
        for (int n = 0; n < 4; ++n) {
            const size_t rowbase = (size_t)(e0 + n * 16 + l15) * 128;
#pragma unroll
            for (int m = 0; m < 2; ++m)
                *(f32x4*)&gout[rowbase + wb + m * 16 + g * 4] = acc2[m][n];
        }

        if (!have) break;
        tile = nxt;
    }
}

extern "C" void kernel_launch(void* const* d_in, const int* in_sizes, int n_in,
                              void* d_out, int out_size, void* d_ws, size_t ws_size,
                              hipStream_t stream) {
    const float* src = (const float*)d_in[0];
    const float* dst = (const float*)d_in[1];
    const float* ea  = (const float*)d_in[2];
    const float* u   = (const float*)d_in[3];
    const int*   bt  = (const int*)d_in[4];
    const float* w1  = (const float*)d_in[5];
    const float* b1  = (const float*)d_in[6];
    const float* w2  = (const float*)d_in[7];
    const float* b2  = (const float*)d_in[8];
    float* out = (float*)d_out;

    edge_mlp<<<GRID, 256, 0, stream>>>(src, dst, ea, u, bt, w1, b1, w2, b2, out);
}

// Round 11
// 290.347 us; speedup vs baseline: 1.9691x; 1.0218x over previous
//
#include <hip/hip_runtime.h>

// EdgeModel: out = relu(x@W1+b1)@W2 + b2 + x, x = [src|dest|ea|u[batch]].
// E=1e6, dims 128. bf16 MFMA 16x16x32, fp32 accum.
// R11: R5 structure exactly, but BOTH weight fragment sets are reloaded from
// global (L2-resident 64KB each) at the TOP of the phase that uses them:
//   - w1t right after bar1 (dead through all of phase 2)
//   - w2t after the h-write (dead through all of phase 1)
// This cuts per-phase max-live to ~132 unified regs, so __launch_bounds__
// (256,3) (168-reg budget) holds WITHOUT the spills of R6/R7/R9/R10.
// w1t loads are issued BEFORE load_pre(nxt): vmcnt completes in-order, so
// waiting for w1t must not queue behind the 9 HBM prefetch loads.

#define E_TOTAL   1000000
#define TILE_M    64
#define NUM_TILES (E_TOTAL / TILE_M)   // 15625
#define GRID      2048

typedef __attribute__((ext_vector_type(8))) __bf16 bf16x8;
typedef __attribute__((ext_vector_type(4))) __bf16 bf16x4;
typedef __attribute__((ext_vector_type(4))) float  f32x4;

__device__ inline bf16x8 pack8(f32x4 v0, f32x4 v1) {
    bf16x8 r;
    r[0] = (__bf16)v0[0]; r[1] = (__bf16)v0[1];
    r[2] = (__bf16)v0[2]; r[3] = (__bf16)v0[3];
    r[4] = (__bf16)v1[0]; r[5] = (__bf16)v1[1];
    r[6] = (__bf16)v1[2]; r[7] = (__bf16)v1[3];
    return r;
}

// row-major [64][128] bf16, 16 groups of 8/row, group XOR (row&15):
// all b128 reads conflict-free.
__device__ inline int swz(int row, int group) {
    return (row * 16 + (group ^ (row & 15))) * 8;
}

__global__ __launch_bounds__(256, 3)
void edge_mlp(const float* __restrict__ gsrc,
              const float* __restrict__ gdst,
              const float* __restrict__ gea,
              const float* __restrict__ gu,
              const int*   __restrict__ gbatch,
              const float* __restrict__ gw1,
              const float* __restrict__ gb1,
              const float* __restrict__ gw2,
              const float* __restrict__ gb2,
              float* __restrict__ gout)
{
    __shared__ __align__(16) __bf16 xs[TILE_M * 128];   // x tile (bf16, swizzled)
    __shared__ __align__(16) __bf16 hl[TILE_M * 128];   // h tile (bf16, swizzled)

    const int tid  = threadIdx.x;
    const int lane = tid & 63;
    const int wid  = tid >> 6;     // wave owns hidden/out-dim rows [wb,wb+32)
    const int l15  = lane & 15;
    const int g    = lane >> 4;
    const int wb   = wid * 32;

    // ---- biases along C rows: b[wb + m*16 + g*4 + r]
    f32x4 b1v[2], b2v[2];
#pragma unroll
    for (int m = 0; m < 2; ++m)
#pragma unroll
        for (int r = 0; r < 4; ++r) {
            b1v[m][r] = gb1[wb + m * 16 + g * 4 + r];
            b2v[m][r] = gb2[wb + m * 16 + g * 4 + r];
        }

    // ---- staging: thread t owns edge-row t>>2, 8-float chunk t&3 ----
    const int srow = tid >> 2;
    const int ssub = tid & 3;

    f32x4 pre[4][2];
    auto load_pre = [&](int t) {
        const int e = t * TILE_M + srow;
        const int bi = gbatch[e];          // first: gates the u gather
        const float* p0 = gsrc + (size_t)e * 32 + ssub * 8;
        const float* p1 = gdst + (size_t)e * 32 + ssub * 8;
        const float* p2 = gea  + (size_t)e * 32 + ssub * 8;
        pre[0][0] = *(const f32x4*)p0; pre[0][1] = *(const f32x4*)(p0 + 4);
        pre[1][0] = *(const f32x4*)p1; pre[1][1] = *(const f32x4*)(p1 + 4);
        pre[2][0] = *(const f32x4*)p2; pre[2][1] = *(const f32x4*)(p2 + 4);
        const float* p3 = gu + (size_t)bi * 32 + ssub * 8;
        pre[3][0] = *(const f32x4*)p3; pre[3][1] = *(const f32x4*)(p3 + 4);
    };

    // weight fragment loader: lane holds W^T[row=wb+m*16+l15][k=ks*32+g*8+j]
    const int wrow0 = wb + l15;        // + m*16
    auto load_wt = [&](const float* gw, bf16x8 (&wt)[2][4]) {
#pragma unroll
        for (int m = 0; m < 2; ++m)
#pragma unroll
            for (int ks = 0; ks < 4; ++ks) {
                bf16x8 t;
#pragma unroll
                for (int j = 0; j < 8; ++j) {
                    const int k = ks * 32 + g * 8 + j;
                    t[j] = (__bf16)gw[k * 128 + wrow0 + m * 16];
                }
                wt[m][ks] = t;
            }
    };

    int tile = blockIdx.x;
    load_pre(tile);

    while (true) {
        // ---- stage x tile into LDS (bf16, swizzled) ----
#pragma unroll
        for (int p = 0; p < 4; ++p)
            *(bf16x8*)&xs[swz(srow, p * 4 + ssub)] = pack8(pre[p][0], pre[p][1]);
        __syncthreads();                                   // bar1

        // ---- W1^T reload FIRST (L2-hit; before the HBM prefetch so the
        //      in-order vmcnt wait for w1t doesn't queue behind it) ----
        bf16x8 w1t[2][4];
        load_wt(gw1, w1t);

        const int  nxt  = tile + GRID;
        const bool have = nxt < NUM_TILES;
        if (have) load_pre(nxt);

        // ---- GEMM1^T: h^T = W1^T @ x^T + b1 ----
        f32x4 acc[2][4];
#pragma unroll
        for (int m = 0; m < 2; ++m)
#pragma unroll
            for (int n = 0; n < 4; ++n)
                acc[m][n] = b1v[m];
#pragma unroll
        for (int ks = 0; ks < 4; ++ks) {
            bf16x8 bf[4];
#pragma unroll
            for (int n = 0; n < 4; ++n)
                bf[n] = *(const bf16x8*)&xs[swz(n * 16 + l15, ks * 4 + g)];
#pragma unroll
            for (int m = 0; m < 2; ++m)
#pragma unroll
                for (int n = 0; n < 4; ++n)
                    acc[m][n] = __builtin_amdgcn_mfma_f32_16x16x32_bf16(
                        w1t[m][ks], bf[n], acc[m][n], 0, 0, 0);
        }

        // ---- ReLU + pack + h -> LDS (b64: 4 consecutive hidden dims) ----
#pragma unroll
        for (int m = 0; m < 2; ++m)
#pragma unroll
            for (int n = 0; n < 4; ++n) {
                f32x4 v = acc[m][n];
                bf16x4 h4;
#pragma unroll
                for (int r = 0; r < 4; ++r) {
                    float x = v[r];
                    h4[r] = (__bf16)(x > 0.f ? x : 0.f);
                }
                const int hid = wb + m * 16 + 4 * g;       // 4-aligned
                *(bf16x4*)&hl[swz(n * 16 + l15, hid >> 3) + (hid & 7)] = h4;
            }

        // ---- W2^T reload (acc dead; ~400cy before first use in GEMM2) ----
        bf16x8 w2t[2][4];
        load_wt(gw2, w2t);

        // ---- acc2 init: bias + residual x (b64 read from xs, pre-bar2) ----
        f32x4 acc2[2][4];
#pragma unroll
        for (int m = 0; m < 2; ++m)
#pragma unroll
            for (int n = 0; n < 4; ++n) {
                const int hid = wb + m * 16 + 4 * g;       // out-dim base, 4-aligned
                bf16x4 rx = *(const bf16x4*)&xs[swz(n * 16 + l15, hid >> 3) + (hid & 7)];
                f32x4 t;
#pragma unroll
                for (int r = 0; r < 4; ++r)
                    t[r] = b2v[m][r] + (float)rx[r];
                acc2[m][n] = t;
            }
        __syncthreads();                                   // bar2

        // ---- GEMM2^T: out^T += W2^T @ h^T ----
#pragma unroll
        for (int ks = 0; ks < 4; ++ks) {
            bf16x8 bh[4];
#pragma unroll
            for (int n = 0; n < 4; ++n)
                bh[n] = *(const bf16x8*)&hl[swz(n * 16 + l15, ks * 4 + g)];
#pragma unroll
            for (int m = 0; m < 2; ++m)
#pragma unroll
                for (int n = 0; n < 4; ++n)
                    acc2[m][n] = __builtin_amdgcn_mfma_f32_16x16x32_bf16(
                        w2t[m][ks], bh[n], acc2[m][n], 0, 0, 0);
        }

        // ---- epilogue: plain float4 stores (4 consecutive out dims) ----
        const int e0 = tile * TILE_M;
#pragma unroll
        for (int n = 0; n < 4; ++n) {
            const size_t rowbase = (size_t)(e0 + n * 16 + l15) * 128;
#pragma unroll
            for (int m = 0; m < 2; ++m)
                *(f32x4*)&gout[rowbase + wb + m * 16 + g * 4] = acc2[m][n];
        }

        if (!have) break;
        tile = nxt;
    }
}

extern "C" void kernel_launch(void* const* d_in, const int* in_sizes, int n_in,
                              void* d_out, int out_size, void* d_ws, size_t ws_size,
                              hipStream_t stream) {
    const float* src = (const float*)d_in[0];
    const float* dst = (const float*)d_in[1];
    const float* ea  = (const float*)d_in[2];
    const float* u   = (const float*)d_in[3];
    const int*   bt  = (const int*)d_in[4];
    const float* w1  = (const float*)d_in[5];
    const float* b1  = (const float*)d_in[6];
    const float* w2  = (const float*)d_in[7];
    const float* b2  = (const float*)d_in[8];
    float* out = (float*)d_out;

    edge_mlp<<<GRID, 256, 0, stream>>>(src, dst, ea, u, bt, w1, b1, w2, b2, out);
}

// Round 12
// 176.443 us; speedup vs baseline: 3.2403x; 1.6456x over previous
//
#include <hip/hip_runtime.h>

// EdgeModel: out = relu(x@W1+b1)@W2 + b2 + x, x = [src|dest|ea|u[batch]].
// E=1e6, dims 128. bf16 MFMA 16x16x32, fp32 accum.
// R12: R5 structure verbatim, minus ~16 regs of natural pressure so the
// ALLOCATOR'S OWN allocation crosses the 3-waves/SIMD threshold (<=170
// unified regs) without forced launch bounds (R6/R7/R9/R10/R11 all proved
// any forced budget spills):
//   - pre[3] (u-part, 8 VGPR) dropped: u is L1-resident 8KB; load at stage
//     time from the prefetched batch index.
//   - persistent b2v (8 VGPR) dropped: reloaded per tile at acc2-init
//     (2x f32x4 L2-hit, ~300cy ahead of use).
// __launch_bounds__(256,2) kept: it is a floor (cap 256), natural alloc
// decides occupancy -> no spill risk; worst case = R5 exactly.

#define E_TOTAL   1000000
#define TILE_M    64
#define NUM_TILES (E_TOTAL / TILE_M)   // 15625
#define GRID      2048

typedef __attribute__((ext_vector_type(8))) __bf16 bf16x8;
typedef __attribute__((ext_vector_type(4))) __bf16 bf16x4;
typedef __attribute__((ext_vector_type(4))) float  f32x4;

__device__ inline bf16x8 pack8(f32x4 v0, f32x4 v1) {
    bf16x8 r;
    r[0] = (__bf16)v0[0]; r[1] = (__bf16)v0[1];
    r[2] = (__bf16)v0[2]; r[3] = (__bf16)v0[3];
    r[4] = (__bf16)v1[0]; r[5] = (__bf16)v1[1];
    r[6] = (__bf16)v1[2]; r[7] = (__bf16)v1[3];
    return r;
}

// row-major [64][128] bf16, 16 groups of 8/row, group XOR (row&15):
// all b128 reads conflict-free.
__device__ inline int swz(int row, int group) {
    return (row * 16 + (group ^ (row & 15))) * 8;
}

__global__ __launch_bounds__(256, 2)
void edge_mlp(const float* __restrict__ gsrc,
              const float* __restrict__ gdst,
              const float* __restrict__ gea,
              const float* __restrict__ gu,
              const int*   __restrict__ gbatch,
              const float* __restrict__ gw1,
              const float* __restrict__ gb1,
              const float* __restrict__ gw2,
              const float* __restrict__ gb2,
              float* __restrict__ gout)
{
    __shared__ __align__(16) __bf16 xs[TILE_M * 128];   // x tile (bf16, swizzled)
    __shared__ __align__(16) __bf16 hl[TILE_M * 128];   // h tile (bf16, swizzled)

    const int tid  = threadIdx.x;
    const int lane = tid & 63;
    const int wid  = tid >> 6;     // wave owns hidden/out-dim rows [wb,wb+32)
    const int l15  = lane & 15;
    const int g    = lane >> 4;
    const int wb   = wid * 32;

    // ---- W1^T and W2^T as A-fragments (persistent, 64 regs):
    //      lane holds W^T[row = wb+m*16+l15][k = ks*32+g*8+j] = gw[k*128+row]
    bf16x8 w1t[2][4], w2t[2][4];
#pragma unroll
    for (int m = 0; m < 2; ++m)
#pragma unroll
        for (int ks = 0; ks < 4; ++ks) {
            bf16x8 t1, t2;
#pragma unroll
            for (int j = 0; j < 8; ++j) {
                const int k = ks * 32 + g * 8 + j;
                const int r = wb + m * 16 + l15;
                t1[j] = (__bf16)gw1[k * 128 + r];
                t2[j] = (__bf16)gw2[k * 128 + r];
            }
            w1t[m][ks] = t1;
            w2t[m][ks] = t2;
        }

    // ---- b1 along C rows (persistent; b2 reloaded per tile) ----
    f32x4 b1v[2];
#pragma unroll
    for (int m = 0; m < 2; ++m)
#pragma unroll
        for (int r = 0; r < 4; ++r)
            b1v[m][r] = gb1[wb + m * 16 + g * 4 + r];

    // ---- staging: thread t owns edge-row t>>2, 8-float chunk t&3 ----
    const int srow = tid >> 2;
    const int ssub = tid & 3;

    f32x4 pre[3][2];   // src/dest/ea only; u loaded at stage time (L1-resident)
    int   preb;        // prefetched batch index
    auto load_pre = [&](int t) {
        const int e = t * TILE_M + srow;
        preb = gbatch[e];
        const float* p0 = gsrc + (size_t)e * 32 + ssub * 8;
        const float* p1 = gdst + (size_t)e * 32 + ssub * 8;
        const float* p2 = gea  + (size_t)e * 32 + ssub * 8;
        pre[0][0] = *(const f32x4*)p0; pre[0][1] = *(const f32x4*)(p0 + 4);
        pre[1][0] = *(const f32x4*)p1; pre[1][1] = *(const f32x4*)(p1 + 4);
        pre[2][0] = *(const f32x4*)p2; pre[2][1] = *(const f32x4*)(p2 + 4);
    };

    int tile = blockIdx.x;
    load_pre(tile);

    while (true) {
        // ---- stage x tile into LDS (bf16, swizzled) ----
#pragma unroll
        for (int p = 0; p < 3; ++p)
            *(bf16x8*)&xs[swz(srow, p * 4 + ssub)] = pack8(pre[p][0], pre[p][1]);
        {   // u part: load now from L1-resident table (bi was prefetched)
            const float* q = gu + (size_t)preb * 32 + ssub * 8;
            f32x4 lo = *(const f32x4*)q;
            f32x4 hi = *(const f32x4*)(q + 4);
            *(bf16x8*)&xs[swz(srow, 12 + ssub)] = pack8(lo, hi);
        }
        __syncthreads();                                   // bar1

        const int  nxt  = tile + GRID;
        const bool have = nxt < NUM_TILES;
        if (have) load_pre(nxt);

        // ---- GEMM1^T: h^T = W1^T @ x^T + b1 ----
        f32x4 acc[2][4];
#pragma unroll
        for (int m = 0; m < 2; ++m)
#pragma unroll
            for (int n = 0; n < 4; ++n)
                acc[m][n] = b1v[m];
#pragma unroll
        for (int ks = 0; ks < 4; ++ks) {
            bf16x8 bf[4];
#pragma unroll
            for (int n = 0; n < 4; ++n)
                bf[n] = *(const bf16x8*)&xs[swz(n * 16 + l15, ks * 4 + g)];
#pragma unroll
            for (int m = 0; m < 2; ++m)
#pragma unroll
                for (int n = 0; n < 4; ++n)
                    acc[m][n] = __builtin_amdgcn_mfma_f32_16x16x32_bf16(
                        w1t[m][ks], bf[n], acc[m][n], 0, 0, 0);
        }

        // ---- ReLU + pack + h -> LDS (b64: 4 consecutive hidden dims) ----
#pragma unroll
        for (int m = 0; m < 2; ++m)
#pragma unroll
            for (int n = 0; n < 4; ++n) {
                f32x4 v = acc[m][n];
                bf16x4 h4;
#pragma unroll
                for (int r = 0; r < 4; ++r) {
                    float x = v[r];
                    h4[r] = (__bf16)(x > 0.f ? x : 0.f);
                }
                const int hid = wb + m * 16 + 4 * g;       // 4-aligned
                *(bf16x4*)&hl[swz(n * 16 + l15, hid >> 3) + (hid & 7)] = h4;
            }

        // ---- b2 reload (L2-hit, ~300cy ahead of GEMM2) ----
        f32x4 b2v[2];
#pragma unroll
        for (int m = 0; m < 2; ++m)
            b2v[m] = *(const f32x4*)&gb2[wb + m * 16 + g * 4];

        // ---- acc2 init: bias + residual x (b64 read from xs, pre-bar2) ----
        f32x4 acc2[2][4];
#pragma unroll
        for (int m = 0; m < 2; ++m)
#pragma unroll
            for (int n = 0; n < 4; ++n) {
                const int hid = wb + m * 16 + 4 * g;       // out-dim base, 4-aligned
                bf16x4 rx = *(const bf16x4*)&xs[swz(n * 16 + l15, hid >> 3) + (hid & 7)];
                f32x4 t;
#pragma unroll
                for (int r = 0; r < 4; ++r)
                    t[r] = b2v[m][r] + (float)rx[r];
                acc2[m][n] = t;
            }
        __syncthreads();                                   // bar2

        // ---- GEMM2^T: out^T += W2^T @ h^T ----
#pragma unroll
        for (int ks = 0; ks < 4; ++ks) {
            bf16x8 bh[4];
#pragma unroll
            for (int n = 0; n < 4; ++n)
                bh[n] = *(const bf16x8*)&hl[swz(n * 16 + l15, ks * 4 + g)];
#pragma unroll
            for (int m = 0; m < 2; ++m)
#pragma unroll
                for (int n = 0; n < 4; ++n)
                    acc2[m][n] = __builtin_amdgcn_mfma_f32_16x16x32_bf16(
                        w2t[m][ks], bh[n], acc2[m][n], 0, 0, 0);
        }

        // ---- epilogue: plain float4 stores (4 consecutive out dims) ----
        const int e0 = tile * TILE_M;
#pragma unroll
        for (int n = 0; n < 4; ++n) {
            const size_t rowbase = (size_t)(e0 + n * 16 + l15) * 128;
#pragma unroll
            for (int m = 0; m < 2; ++m)
                *(f32x4*)&gout[rowbase + wb + m * 16 + g * 4] = acc2[m][n];
        }

        if (!have) break;
        tile = nxt;
    }
}

extern "C" void kernel_launch(void* const* d_in, const int* in_sizes, int n_in,
                              void* d_out, int out_size, void* d_ws, size_t ws_size,
                              hipStream_t stream) {
    const float* src = (const float*)d_in[0];
    const float* dst = (const float*)d_in[1];
    const float* ea  = (const float*)d_in[2];
    const float* u   = (const float*)d_in[3];
    const int*   bt  = (const int*)d_in[4];
    const float* w1  = (const float*)d_in[5];
    const float* b1  = (const float*)d_in[6];
    const float* w2  = (const float*)d_in[7];
    const float* b2  = (const float*)d_in[8];
    float* out = (float*)d_out;

    edge_mlp<<<GRID, 256, 0, stream>>>(src, dst, ea, u, bt, w1, b1, w2, b2, out);
}